// Round 4
// baseline (169.368 us; speedup 1.0000x reference)
//
#include <hip/hip_runtime.h>
#include <math.h>

#define BB 64
#define SS 8192
#define IN_DIM 512
#define OUT_DIM 128
#define DVV 128
#define CHUNK 256
#define NCHUNK (SS / CHUNK)          // 32
#define NGRP 8                       // 32-lane groups per 256-thread block
#define RPG (CHUNK / NGRP)           // 32 rows per group
#define NPART (NCHUNK * NGRP)        // 256 partials per batch

// Kernel 1: qt[b] = (Wk @ (q[b] @ Wq)) / sqrt(OUT_DIM)   (512 threads, 4-way split-K)
__global__ __launch_bounds__(512) void qt_kernel(const float* __restrict__ q,
                          const float* __restrict__ Wq,
                          const float* __restrict__ Wk,
                          float* __restrict__ qt) {
    int b = blockIdx.x;
    int t = threadIdx.x;
    int e = t & 127;          // output index
    int h = t >> 7;           // split 0..3
    __shared__ float part[4][OUT_DIM];
    __shared__ float qs[OUT_DIM];

    const float* qb = q + (size_t)b * IN_DIM;
    float acc = 0.f;
    for (int i = h * (IN_DIM / 4); i < (h + 1) * (IN_DIM / 4); ++i)
        acc = fmaf(qb[i], Wq[(size_t)i * OUT_DIM + e], acc);
    part[h][e] = acc;
    __syncthreads();
    if (h == 0) qs[e] = part[0][e] + part[1][e] + part[2][e] + part[3][e];
    __syncthreads();

    float a2 = 0.f;
    const float* wkrow = Wk + (size_t)e * OUT_DIM;
    for (int i = h * (OUT_DIM / 4); i < (h + 1) * (OUT_DIM / 4); ++i)
        a2 = fmaf(wkrow[i], qs[i], a2);
    part[h][e] = a2;
    __syncthreads();
    if (h == 0)
        qt[(size_t)b * OUT_DIM + e] =
            (part[0][e] + part[1][e] + part[2][e] + part[3][e]) * 0.08838834764831845f;
}

// Kernel 2: barrier-free, LDS-free streaming kernel.
// Each 32-lane group independently owns 32 rows (rows g+8j of its chunk).
// Phase A: stream k, butterfly-reduce dot -> every lane of the group holds
// s[j] for all its rows in registers. Phase B: stream v with exp-weights.
// Per-group (m, l, ctx[128]) partial written to global. NO __syncthreads.
__global__ __launch_bounds__(256) void partial_kernel(
    const float* __restrict__ k, const float* __restrict__ v,
    const float* __restrict__ qt, float* __restrict__ ml,
    float* __restrict__ ctx) {
    int blk = blockIdx.x;
    int b = blk >> 5;          // / NCHUNK
    int c = blk & 31;
    int s0 = c * CHUNK;
    int t = threadIdx.x;
    int g = t >> 5;            // group 0..7
    int l32 = t & 31;

    float4 qv = ((const float4*)(qt + (size_t)b * OUT_DIM))[l32];

    // float4 pointers; row stride = 32 float4s; group g handles rows g+8j
    const float4* k4 = (const float4*)(k + (size_t)b * SS * OUT_DIM)
                       + (size_t)(s0 + g) * (OUT_DIM / 4) + l32;
    const float4* v4 = (const float4*)(v + (size_t)b * SS * DVV)
                       + (size_t)(s0 + g) * (DVV / 4) + l32;

    float s[RPG];
    float m = -INFINITY;
    #pragma unroll
    for (int j = 0; j < RPG; ++j) {
        float4 kv = k4[j * 8 * (OUT_DIM / 4)];
        float p = kv.x * qv.x + kv.y * qv.y + kv.z * qv.z + kv.w * qv.w;
        p += __shfl_xor(p, 1);
        p += __shfl_xor(p, 2);
        p += __shfl_xor(p, 4);
        p += __shfl_xor(p, 8);
        p += __shfl_xor(p, 16);
        s[j] = p;
        m = fmaxf(m, p);
    }

    float l = 0.f;
    float4 acc = make_float4(0.f, 0.f, 0.f, 0.f);
    #pragma unroll
    for (int j = 0; j < RPG; ++j) {
        float4 vv = v4[j * 8 * (DVV / 4)];
        float w = __expf(s[j] - m);
        l += w;
        acc.x = fmaf(w, vv.x, acc.x);
        acc.y = fmaf(w, vv.y, acc.y);
        acc.z = fmaf(w, vv.z, acc.z);
        acc.w = fmaf(w, vv.w, acc.w);
    }

    size_t gi = (size_t)blk * NGRP + g;      // (b*NCHUNK+c)*8+g
    ((float4*)(ctx + gi * DVV))[l32] = acc;
    if (l32 == 0) {
        ml[gi * 2 + 0] = m;
        ml[gi * 2 + 1] = l;
    }
}

// Kernel 3: merge 256 group-partials per batch with max-rescaling.
__global__ __launch_bounds__(256) void combine_kernel(
    const float* __restrict__ ml, const float* __restrict__ ctx,
    float* __restrict__ out) {
    int b = blockIdx.x;
    int t = threadIdx.x;    // 256
    __shared__ float sm[NPART], sl[NPART], sw[NPART];

    sm[t] = ml[((size_t)b * NPART + t) * 2 + 0];
    sl[t] = ml[((size_t)b * NPART + t) * 2 + 1];
    __syncthreads();

    float M = -INFINITY;
    #pragma unroll 8
    for (int i = 0; i < NPART; ++i) M = fmaxf(M, sm[i]);
    sw[t] = __expf(sm[t] - M);
    __syncthreads();

    if (t < DVV) {
        float L = 0.f;
        #pragma unroll 8
        for (int i = 0; i < NPART; ++i) L = fmaf(sl[i], sw[i], L);
        float acc = 0.f;
        const float* cb = ctx + (size_t)b * NPART * DVV + t;
        #pragma unroll 8
        for (int i = 0; i < NPART; ++i)
            acc = fmaf(sw[i], cb[(size_t)i * DVV], acc);
        out[(size_t)b * DVV + t] = acc / L;
    }
}

extern "C" void kernel_launch(void* const* d_in, const int* in_sizes, int n_in,
                              void* d_out, int out_size, void* d_ws, size_t ws_size,
                              hipStream_t stream) {
    const float* k  = (const float*)d_in[0];
    const float* q  = (const float*)d_in[1];
    const float* v  = (const float*)d_in[2];
    const float* Wk = (const float*)d_in[3];
    const float* Wq = (const float*)d_in[4];
    float* out = (float*)d_out;

    float* qt  = (float*)d_ws;                     // B*128
    float* ml  = qt + BB * OUT_DIM;                // B*256*2
    float* ctx = ml + (size_t)BB * NPART * 2;      // B*256*128 (8.4 MB)

    qt_kernel<<<BB, 512, 0, stream>>>(q, Wq, Wk, qt);
    partial_kernel<<<BB * NCHUNK, 256, 0, stream>>>(k, v, qt, ml, ctx);
    combine_kernel<<<BB, 256, 0, stream>>>(ml, ctx, out);
}